// Round 10
// baseline (138.403 us; speedup 1.0000x reference)
//
#include <hip/hip_runtime.h>

// Problem: BS=64, N=1024, XC=1024, K=256, YS=768
//   y_k[b,k]   = sum_s y[b,s] * W_y[k,s]
//   z[b,n,k]   = tanh( sum_c x[b,n,c]*W_ch[k,c] + b_ch[k] + y_k[b,k] )
//   out[b*n,k] = softmax_k(z)
// bf16 MFMA GEMM (f32 acc) fused with tanh+softmax epilogue.
// R10: SEQUENTIAL-STREAM staging. Each block (BM=32) streams its whole
//      128KB A-panel as 32 contiguous 4KB row loads (fill-kernel-like
//      DRAM pattern), converts to bf16 into a single 64KB LDS tile, then
//      runs all 16 K-steps BARRIER-FREE from LDS (B double-buffered in
//      regs, counted vmcnt). 2 barriers/block instead of 17.

#define XC    1024
#define KOUT  256
#define NT    16        // K-steps: 1024 / 64
#define LDSZ  65536     // 16 tiles x (32 rows x 64 cols bf16) = 64KB

typedef float        f32x4_t  __attribute__((ext_vector_type(4)));
typedef unsigned int u32x4_t  __attribute__((ext_vector_type(4)));
typedef unsigned int u32x2_t  __attribute__((ext_vector_type(2)));
typedef __bf16       bf16x8_t __attribute__((ext_vector_type(8)));

__device__ __forceinline__ unsigned short f2bf(float f) {
  unsigned int u = __float_as_uint(f);
  u += 0x7fffu + ((u >> 16) & 1u);        // RNE
  return (unsigned short)(u >> 16);
}

__device__ __forceinline__ float fast_tanh(float v) {
  float e = __expf(2.0f * v);
  return 1.0f - 2.0f / (e + 1.0f);
}

// lgkm-only barrier: ds_writes visible, global loads STAY IN FLIGHT.
#define LGKM_BARRIER() do {                                  \
    asm volatile("s_waitcnt lgkmcnt(0)" ::: "memory");       \
    __builtin_amdgcn_s_barrier();                            \
    __builtin_amdgcn_sched_barrier(0);                       \
  } while (0)

// ---- prep kernel: blocks 0..255 convert W_ch -> fragment-ordered bf16;
//      blocks 256..319 compute bias[b][k] = y[b]·W_y[k] + b_ch[k] (f32).
__global__ void prep_kernel(const float* __restrict__ Wch,
                            const float* __restrict__ y,
                            const float* __restrict__ Wy,
                            const float* __restrict__ bch,
                            unsigned short* __restrict__ wbf,
                            float* __restrict__ biasws) {
  if (blockIdx.x < 256) {
    const int k = blockIdx.x;            // 0..255
    const int u = threadIdx.x;           // 0..255 ; c0 = 4u
    f32x4_t v = ((const f32x4_t*)(Wch + k * XC))[u];
    const int c0   = u << 2;
    const int t    = c0 >> 6;            // K-step tile
    const int ch   = (c0 & 63) >> 3;     // 16B chunk within tile
    const int kk   = ch >> 2;
    const int lg   = ch & 3;
    const int half = (c0 >> 2) & 1;      // which 8B of the 16B chunk
    const int wv   = k >> 6;
    const int ni   = (k >> 4) & 3;
    const int lr   = k & 15;
    const int lane = (lg << 4) | lr;
    unsigned int lo = (unsigned int)f2bf(v.x) | ((unsigned int)f2bf(v.y) << 16);
    unsigned int hi = (unsigned int)f2bf(v.z) | ((unsigned int)f2bf(v.w) << 16);
    char* p = (char*)wbf +
              ((size_t)((((t << 2) + wv) * 2 + kk) * 4 + ni) << 10) +
              (lane << 4) + (half << 3);
    *(u32x2_t*)p = (u32x2_t){lo, hi};
  } else {
    __shared__ __align__(16) float ys[768];
    const int b = blockIdx.x - 256;      // 0..63
    const int k = threadIdx.x;           // 0..255
    for (int i = k; i < 768; i += 256) ys[i] = y[b * 768 + i];
    __syncthreads();
    const f32x4_t* w4 = (const f32x4_t*)(Wy + k * 768);
    const f32x4_t* y4 = (const f32x4_t*)ys;
    float s = 0.f;
#pragma unroll 8
    for (int i = 0; i < 192; ++i) {
      f32x4_t w = w4[i], a = y4[i];
      s = fmaf(w.x, a.x, s); s = fmaf(w.y, a.y, s);
      s = fmaf(w.z, a.z, s); s = fmaf(w.w, a.w, s);
    }
    biasws[b * 256 + k] = s + bch[k];
  }
}

// ---- main fused kernel: 32 rows/block x full 256 cols.
// Stage whole A-panel sequentially -> LDS (bf16, XOR swizzle), then 16
// barrier-free K-steps (A from LDS, B from L2 to dbuf regs), epilogue.
__global__ __launch_bounds__(256, 2) void fused_kernel(
    const float* __restrict__ x, const unsigned short* __restrict__ wbf,
    const float* __restrict__ bias, float* __restrict__ out) {
  __shared__ __align__(16) unsigned char smem[LDSZ];
  const int tid = threadIdx.x;
  const int l   = tid & 63;
  const int w   = tid >> 6;            // wave 0..3 -> output cols [64w,64w+64)
  const int lr  = l & 15;
  const int lg  = l >> 4;
  const int m0  = blockIdx.x << 5;     // first of 32 rows
  const int bidx = m0 >> 10;           // batch index
  const int t0  = blockIdx.x & 15;     // K-phase rotation (L2/B spread)

  f32x4_t acc[2][4];
#pragma unroll
  for (int i = 0; i < 2; ++i)
#pragma unroll
    for (int j = 0; j < 4; ++j) acc[i][j] = (f32x4_t){0.f, 0.f, 0.f, 0.f};

  const f32x4_t* xbase = (const f32x4_t*)(x + (size_t)m0 * XC);
  const char* wsrc = (const char*)wbf + (w << 13) + (l << 4);
  f32x4_t G0[8], G1[8];                // staging row groups (static idx only)
  bf16x8_t bfrA[8], bfrB[8];           // B frags [kk*4+nj], double-buffered

  // LOADG: rows i0..i0+7, each row = one fully-coalesced 4KB instruction
#define LOADG(dst, i0) do {                                                  \
    _Pragma("unroll")                                                        \
    for (int j = 0; j < 8; ++j)                                              \
      dst[j] = xbase[(size_t)((i0) + j) * 256 + tid];                        \
  } while (0)

  // WRITEG: cvt f32->bf16, swizzled ds_write. tid maps: tile=tid>>4,
  // half-chunk cc=tid&15 -> stored 16B chunk = (cc>>1)^(row&7), half=cc&1.
#define WRITEG(src, i0) do {                                                 \
    _Pragma("unroll")                                                        \
    for (int j = 0; j < 8; ++j) {                                            \
      const int row = (i0) + j;                                              \
      unsigned int lo = (unsigned int)f2bf(src[j].x) |                       \
                        ((unsigned int)f2bf(src[j].y) << 16);                \
      unsigned int hi = (unsigned int)f2bf(src[j].z) |                       \
                        ((unsigned int)f2bf(src[j].w) << 16);                \
      char* p = (char*)smem + ((tid >> 4) << 12) + row * 128 +               \
                ((((tid & 15) >> 1) ^ (row & 7)) << 4) + ((tid & 1) << 3);   \
      *(u32x2_t*)p = (u32x2_t){lo, hi};                                      \
    }                                                                        \
  } while (0)

#define LOADB(dst, tt) do {                                                  \
    const char* g = wsrc + (size_t)(tt) * 32768;                             \
    _Pragma("unroll")                                                        \
    for (int f = 0; f < 8; ++f)                                              \
      dst[f] = __builtin_bit_cast(bf16x8_t, *(const u32x4_t*)(g + (f << 10)));\
  } while (0)

  // COMPUTE_T: A from LDS tile tt (runtime addr ok), B from named regs.
#define COMPUTE_T(tt, bsrc) do {                                             \
    const u32x4_t* aB = (const u32x4_t*)(smem + ((tt) << 12));               \
    _Pragma("unroll")                                                        \
    for (int kk = 0; kk < 2; ++kk) {                                         \
      const int cs = ((kk << 2) | lg) ^ (lr & 7);                            \
      bf16x8_t afr[2];                                                       \
      _Pragma("unroll")                                                      \
      for (int mi = 0; mi < 2; ++mi)                                         \
        afr[mi] = __builtin_bit_cast(bf16x8_t, aB[(((mi << 4) + lr) << 3) + cs]);\
      _Pragma("unroll")                                                      \
      for (int mi = 0; mi < 2; ++mi)                                         \
        _Pragma("unroll")                                                    \
        for (int nj = 0; nj < 4; ++nj)                                       \
          acc[mi][nj] = __builtin_amdgcn_mfma_f32_16x16x32_bf16(             \
              afr[mi], bsrc[(kk << 2) | nj], acc[mi][nj], 0, 0, 0);          \
    }                                                                        \
  } while (0)

  // ---- staging: 128KB sequential stream, 2-deep group pipeline
  LOADG(G0, 0);
  LOADG(G1, 8);
  WRITEG(G0, 0);         // waits G0 arrivals (counted; G1 stays in flight)
  LOADG(G0, 16);
  WRITEG(G1, 8);
  LOADG(G1, 24);
  WRITEG(G0, 16);
  WRITEG(G1, 24);
  LOADB(bfrA, t0);       // first B tile behind the stream (L2 fast)
  LGKM_BARRIER();        // A-panel visible to all waves; bfrA in flight

  // ---- 16 barrier-free K-steps; compiler inserts counted vmcnt for bfr
#pragma unroll
  for (int s = 0; s < NT; s += 2) {
    LOADB(bfrB, ((s + 1 + t0) & 15));
    COMPUTE_T(((s + t0) & 15), bfrA);
    if (s + 2 < NT) LOADB(bfrA, ((s + 2 + t0) & 15));
    COMPUTE_T(((s + 1 + t0) & 15), bfrB);
  }
  __syncthreads();       // all tiles consumed before epilogue aliases smem

#undef LOADG
#undef WRITEG
#undef LOADB
#undef COMPUTE_T

  // ---- epilogue: tanh, row-softmax over 256 cols, store
  float* wred    = (float*)smem;           // [4 waves][32 rows]
  float* rowstat = (float*)(smem + 512);   // [32 rows]

  float brow[4];
#pragma unroll
  for (int ni = 0; ni < 4; ++ni)
    brow[ni] = bias[(bidx << 8) + (w << 6) + (ni << 4) + lr];

#pragma unroll
  for (int mi = 0; mi < 2; ++mi)
#pragma unroll
    for (int ni = 0; ni < 4; ++ni)
#pragma unroll
      for (int r = 0; r < 4; ++r)
        acc[mi][ni][r] = fast_tanh(acc[mi][ni][r] + brow[ni]);

  // per-row max: 4 local cols, then butterfly over the 16-lane col group
#pragma unroll
  for (int mi = 0; mi < 2; ++mi)
#pragma unroll
    for (int r = 0; r < 4; ++r) {
      float m = fmaxf(fmaxf(acc[mi][0][r], acc[mi][1][r]),
                      fmaxf(acc[mi][2][r], acc[mi][3][r]));
      m = fmaxf(m, __shfl_xor(m, 1));
      m = fmaxf(m, __shfl_xor(m, 2));
      m = fmaxf(m, __shfl_xor(m, 4));
      m = fmaxf(m, __shfl_xor(m, 8));
      if (lr == 0) wred[(w << 5) + (mi << 4) + (lg << 2) + r] = m;
    }
  __syncthreads();
  if (tid < 32)
    rowstat[tid] = fmaxf(fmaxf(wred[tid], wred[32 + tid]),
                         fmaxf(wred[64 + tid], wred[96 + tid]));
  __syncthreads();

  // exp + per-row sum
#pragma unroll
  for (int mi = 0; mi < 2; ++mi)
#pragma unroll
    for (int r = 0; r < 4; ++r) {
      const int row = (mi << 4) + (lg << 2) + r;
      const float m = rowstat[row];
      float s = 0.f;
#pragma unroll
      for (int ni = 0; ni < 4; ++ni) {
        float e = __expf(acc[mi][ni][r] - m);
        acc[mi][ni][r] = e;
        s += e;
      }
      s += __shfl_xor(s, 1);
      s += __shfl_xor(s, 2);
      s += __shfl_xor(s, 4);
      s += __shfl_xor(s, 8);
      if (lr == 0) wred[(w << 5) + row] = s;
    }
  __syncthreads();
  if (tid < 32)
    rowstat[tid] = 1.0f / (wred[tid] + wred[32 + tid] +
                           wred[64 + tid] + wred[96 + tid]);
  __syncthreads();

  // normalize + store (16 lanes = 64B dense segments)
#pragma unroll
  for (int mi = 0; mi < 2; ++mi)
#pragma unroll
    for (int r = 0; r < 4; ++r) {
      const int row = (mi << 4) + (lg << 2) + r;
      const float rinv = rowstat[row];
      float* orow = out + (size_t)(m0 + row) * KOUT + (w << 6) + lr;
#pragma unroll
      for (int ni = 0; ni < 4; ++ni)
        orow[ni << 4] = acc[mi][ni][r] * rinv;
    }
}

extern "C" void kernel_launch(void* const* d_in, const int* in_sizes, int n_in,
                              void* d_out, int out_size, void* d_ws, size_t ws_size,
                              hipStream_t stream) {
  (void)in_sizes; (void)n_in; (void)out_size; (void)ws_size;
  const float* x   = (const float*)d_in[0];
  const float* y   = (const float*)d_in[1];
  const float* Wch = (const float*)d_in[2];
  const float* bch = (const float*)d_in[3];
  const float* Wy  = (const float*)d_in[4];
  float* out = (float*)d_out;
  unsigned short* wbf = (unsigned short*)d_ws;                 // 512 KB
  float* biasws = (float*)((char*)d_ws + 512 * 1024);          // 64 KB

  hipLaunchKernelGGL(prep_kernel, dim3(320), dim3(256), 0, stream,
                     Wch, y, Wy, bch, wbf, biasws);
  hipLaunchKernelGGL(fused_kernel, dim3(2048), dim3(256), 0, stream,
                     x, wbf, biasws, out);
}

// Round 11
// 130.401 us; speedup vs baseline: 1.0614x; 1.0614x over previous
//
#include <hip/hip_runtime.h>

// Problem: BS=64, N=1024, XC=1024, K=256, YS=768
//   y_k[b,k]   = sum_s y[b,s] * W_y[k,s]
//   z[b,n,k]   = tanh( sum_c x[b,n,c]*W_ch[k,c] + b_ch[k] + y_k[b,k] )
//   out[b*n,k] = softmax_k(z)
// bf16 MFMA GEMM (f32 acc) fused with tanh+softmax epilogue.
// R11: QUARTER-STREAMED staging. R10 showed fused = 154us at 0.93 TB/s --
//      staging burst then HBM-silent K-loop = phase serialization. Now the
//      A-panel streams in 4 column-quarters (1KB-contiguous per row),
//      double-buffered 16KB LDS; LOADG for quarter q+1 issues inside the
//      compute of quarter q, so HBM stays busy through the whole K-loop.
//      One lgkm barrier per 4 K-steps; 3 blocks/CU (12 waves).

#define XC    1024
#define KOUT  256
#define LDSZ  32768     // 2 x 16KB quarter buffers (epilogue aliases)

typedef float        f32x4_t  __attribute__((ext_vector_type(4)));
typedef unsigned int u32x4_t  __attribute__((ext_vector_type(4)));
typedef unsigned int u32x2_t  __attribute__((ext_vector_type(2)));
typedef __bf16       bf16x8_t __attribute__((ext_vector_type(8)));

__device__ __forceinline__ unsigned short f2bf(float f) {
  unsigned int u = __float_as_uint(f);
  u += 0x7fffu + ((u >> 16) & 1u);        // RNE
  return (unsigned short)(u >> 16);
}

__device__ __forceinline__ float fast_tanh(float v) {
  float e = __expf(2.0f * v);
  return 1.0f - 2.0f / (e + 1.0f);
}

// lgkm-only barrier: ds_writes visible, global loads STAY IN FLIGHT.
#define LGKM_BARRIER() do {                                  \
    asm volatile("s_waitcnt lgkmcnt(0)" ::: "memory");       \
    __builtin_amdgcn_s_barrier();                            \
    __builtin_amdgcn_sched_barrier(0);                       \
  } while (0)

// ---- prep kernel: blocks 0..255 convert W_ch -> fragment-ordered bf16;
//      blocks 256..319 compute bias[b][k] = y[b]·W_y[k] + b_ch[k] (f32).
__global__ void prep_kernel(const float* __restrict__ Wch,
                            const float* __restrict__ y,
                            const float* __restrict__ Wy,
                            const float* __restrict__ bch,
                            unsigned short* __restrict__ wbf,
                            float* __restrict__ biasws) {
  if (blockIdx.x < 256) {
    const int k = blockIdx.x;            // 0..255
    const int u = threadIdx.x;           // 0..255 ; c0 = 4u
    f32x4_t v = ((const f32x4_t*)(Wch + k * XC))[u];
    const int c0   = u << 2;
    const int t    = c0 >> 6;            // K-step tile
    const int ch   = (c0 & 63) >> 3;     // 16B chunk within tile
    const int kk   = ch >> 2;
    const int lg   = ch & 3;
    const int half = (c0 >> 2) & 1;      // which 8B of the 16B chunk
    const int wv   = k >> 6;
    const int ni   = (k >> 4) & 3;
    const int lr   = k & 15;
    const int lane = (lg << 4) | lr;
    unsigned int lo = (unsigned int)f2bf(v.x) | ((unsigned int)f2bf(v.y) << 16);
    unsigned int hi = (unsigned int)f2bf(v.z) | ((unsigned int)f2bf(v.w) << 16);
    char* p = (char*)wbf +
              ((size_t)((((t << 2) + wv) * 2 + kk) * 4 + ni) << 10) +
              (lane << 4) + (half << 3);
    *(u32x2_t*)p = (u32x2_t){lo, hi};
  } else {
    __shared__ __align__(16) float ys[768];
    const int b = blockIdx.x - 256;      // 0..63
    const int k = threadIdx.x;           // 0..255
    for (int i = k; i < 768; i += 256) ys[i] = y[b * 768 + i];
    __syncthreads();
    const f32x4_t* w4 = (const f32x4_t*)(Wy + k * 768);
    const f32x4_t* y4 = (const f32x4_t*)ys;
    float s = 0.f;
#pragma unroll 8
    for (int i = 0; i < 192; ++i) {
      f32x4_t w = w4[i], a = y4[i];
      s = fmaf(w.x, a.x, s); s = fmaf(w.y, a.y, s);
      s = fmaf(w.z, a.z, s); s = fmaf(w.w, a.w, s);
    }
    biasws[b * 256 + k] = s + bch[k];
  }
}

// ---- main fused kernel: 32 rows/block x full 256 cols, 4 waves x 64 cols.
__global__ __launch_bounds__(256, 3) void fused_kernel(
    const float* __restrict__ x, const unsigned short* __restrict__ wbf,
    const float* __restrict__ bias, float* __restrict__ out) {
  __shared__ __align__(16) unsigned char smem[LDSZ];
  const int tid = threadIdx.x;
  const int l   = tid & 63;
  const int w   = tid >> 6;            // wave 0..3 -> output cols [64w,64w+64)
  const int lr  = l & 15;
  const int lg  = l >> 4;
  const int m0  = blockIdx.x << 5;     // first of 32 rows
  const int bidx = m0 >> 10;           // batch index
  const int r0  = blockIdx.x & 3;      // quarter rotation (channel spread)

  f32x4_t acc[2][4];
#pragma unroll
  for (int i = 0; i < 2; ++i)
#pragma unroll
    for (int j = 0; j < 4; ++j) acc[i][j] = (f32x4_t){0.f, 0.f, 0.f, 0.f};

  const char* xpanel = (const char*)x + ((size_t)m0 << 12);
  const char* wsrc   = (const char*)wbf + (w << 13) + (l << 4);
  f32x4_t G[8];                        // one quarter's rows (8 per thread)
  bf16x8_t bfrA[8], bfrB[8];           // B frags [kk*4+nj], double-buffered

  // LOADG: quarter qp (physical 0..3): each wave-instr = 1KB contiguous
#define LOADG(qp) do {                                                       \
    _Pragma("unroll")                                                        \
    for (int j = 0; j < 8; ++j)                                              \
      G[j] = *(const f32x4_t*)(xpanel + (size_t)((j << 2) + w) * 4096 +      \
                               ((qp) << 10) + (l << 4));                     \
  } while (0)

  // WRITEG: cvt f32->bf16, swizzled ds_write into 4 tiles of buf
#define WRITEG(buf) do {                                                     \
    _Pragma("unroll")                                                        \
    for (int j = 0; j < 8; ++j) {                                            \
      const int row = (j << 2) + w;                                          \
      unsigned int lo = (unsigned int)f2bf(G[j].x) |                         \
                        ((unsigned int)f2bf(G[j].y) << 16);                  \
      unsigned int hi = (unsigned int)f2bf(G[j].z) |                         \
                        ((unsigned int)f2bf(G[j].w) << 16);                  \
      char* p = (char*)smem + ((buf) << 14) + ((l >> 4) << 12) + row * 128 + \
                ((((l & 15) >> 1) ^ (row & 7)) << 4) + ((l & 1) << 3);       \
      *(u32x2_t*)p = (u32x2_t){lo, hi};                                      \
    }                                                                        \
  } while (0)

#define LOADB(dst, tg) do {                                                  \
    const char* g = wsrc + (size_t)(tg) * 32768;                             \
    _Pragma("unroll")                                                        \
    for (int f = 0; f < 8; ++f)                                              \
      dst[f] = __builtin_bit_cast(bf16x8_t, *(const u32x4_t*)(g + (f << 10)));\
  } while (0)

#define COMPUTE(buf, tl, bsrc) do {                                          \
    const u32x4_t* aB = (const u32x4_t*)(smem + ((buf) << 14) + ((tl) << 12));\
    _Pragma("unroll")                                                        \
    for (int kk = 0; kk < 2; ++kk) {                                         \
      const int cs = ((kk << 2) | lg) ^ (lr & 7);                            \
      bf16x8_t afr[2];                                                       \
      _Pragma("unroll")                                                      \
      for (int mi = 0; mi < 2; ++mi)                                         \
        afr[mi] = __builtin_bit_cast(bf16x8_t, aB[(((mi << 4) + lr) << 3) + cs]);\
      _Pragma("unroll")                                                      \
      for (int mi = 0; mi < 2; ++mi)                                         \
        _Pragma("unroll")                                                    \
        for (int nj = 0; nj < 4; ++nj)                                       \
          acc[mi][nj] = __builtin_amdgcn_mfma_f32_16x16x32_bf16(             \
              afr[mi], bsrc[(kk << 2) | nj], acc[mi][nj], 0, 0, 0);          \
    }                                                                        \
  } while (0)

  // physical quarter and tile indices (runtime values, never reg indices)
#define QP(q)   (((q) + r0) & 3)
#define TG(q,s) ((QP(q) << 2) | (s))

  // QUARTER(q): buf=q&1 literal; even global steps compute bfrA, odd bfrB.
#define QUARTER(q) do {                                                      \
    if ((q) > 0) { WRITEG((q) & 1); LGKM_BARRIER(); }                        \
    LOADB(bfrB, TG(q, 1));                                                   \
    if ((q) < 3) LOADG(QP((q) + 1));                                         \
    COMPUTE((q) & 1, 0, bfrA);                                               \
    LOADB(bfrA, TG(q, 2));                                                   \
    COMPUTE((q) & 1, 1, bfrB);                                               \
    LOADB(bfrB, TG(q, 3));                                                   \
    COMPUTE((q) & 1, 2, bfrA);                                               \
    if ((q) < 3) LOADB(bfrA, TG((q) + 1, 0));                                \
    COMPUTE((q) & 1, 3, bfrB);                                               \
  } while (0)

  // prologue: stream quarter 0, first B tile; stage into buf0
  LOADG(QP(0));
  LOADB(bfrA, TG(0, 0));
  WRITEG(0);               // drains G (B stays in flight)
  LGKM_BARRIER();

  QUARTER(0);
  QUARTER(1);
  QUARTER(2);
  QUARTER(3);

  __syncthreads();         // all computes done before epilogue aliases smem

#undef LOADG
#undef WRITEG
#undef LOADB
#undef COMPUTE
#undef QP
#undef TG
#undef QUARTER

  // ---- epilogue: tanh, row-softmax over 256 cols, store
  float* wred    = (float*)smem;           // [4 waves][32 rows]
  float* rowstat = (float*)(smem + 512);   // [32 rows]

  float brow[4];
#pragma unroll
  for (int ni = 0; ni < 4; ++ni)
    brow[ni] = bias[(bidx << 8) + (w << 6) + (ni << 4) + lr];

#pragma unroll
  for (int mi = 0; mi < 2; ++mi)
#pragma unroll
    for (int ni = 0; ni < 4; ++ni)
#pragma unroll
      for (int r = 0; r < 4; ++r)
        acc[mi][ni][r] = fast_tanh(acc[mi][ni][r] + brow[ni]);

  // per-row max: 4 local cols, then butterfly over the 16-lane col group
#pragma unroll
  for (int mi = 0; mi < 2; ++mi)
#pragma unroll
    for (int r = 0; r < 4; ++r) {
      float m = fmaxf(fmaxf(acc[mi][0][r], acc[mi][1][r]),
                      fmaxf(acc[mi][2][r], acc[mi][3][r]));
      m = fmaxf(m, __shfl_xor(m, 1));
      m = fmaxf(m, __shfl_xor(m, 2));
      m = fmaxf(m, __shfl_xor(m, 4));
      m = fmaxf(m, __shfl_xor(m, 8));
      if (lr == 0) wred[(w << 5) + (mi << 4) + (lg << 2) + r] = m;
    }
  __syncthreads();
  if (tid < 32)
    rowstat[tid] = fmaxf(fmaxf(wred[tid], wred[32 + tid]),
                         fmaxf(wred[64 + tid], wred[96 + tid]));
  __syncthreads();

  // exp + per-row sum
#pragma unroll
  for (int mi = 0; mi < 2; ++mi)
#pragma unroll
    for (int r = 0; r < 4; ++r) {
      const int row = (mi << 4) + (lg << 2) + r;
      const float m = rowstat[row];
      float s = 0.f;
#pragma unroll
      for (int ni = 0; ni < 4; ++ni) {
        float e = __expf(acc[mi][ni][r] - m);
        acc[mi][ni][r] = e;
        s += e;
      }
      s += __shfl_xor(s, 1);
      s += __shfl_xor(s, 2);
      s += __shfl_xor(s, 4);
      s += __shfl_xor(s, 8);
      if (lr == 0) wred[(w << 5) + row] = s;
    }
  __syncthreads();
  if (tid < 32)
    rowstat[tid] = 1.0f / (wred[tid] + wred[32 + tid] +
                           wred[64 + tid] + wred[96 + tid]);
  __syncthreads();

  // normalize + store (16 lanes = 64B dense segments)
#pragma unroll
  for (int mi = 0; mi < 2; ++mi)
#pragma unroll
    for (int r = 0; r < 4; ++r) {
      const int row = (mi << 4) + (lg << 2) + r;
      const float rinv = rowstat[row];
      float* orow = out + (size_t)(m0 + row) * KOUT + (w << 6) + lr;
#pragma unroll
      for (int ni = 0; ni < 4; ++ni)
        orow[ni << 4] = acc[mi][ni][r] * rinv;
    }
}

extern "C" void kernel_launch(void* const* d_in, const int* in_sizes, int n_in,
                              void* d_out, int out_size, void* d_ws, size_t ws_size,
                              hipStream_t stream) {
  (void)in_sizes; (void)n_in; (void)out_size; (void)ws_size;
  const float* x   = (const float*)d_in[0];
  const float* y   = (const float*)d_in[1];
  const float* Wch = (const float*)d_in[2];
  const float* bch = (const float*)d_in[3];
  const float* Wy  = (const float*)d_in[4];
  float* out = (float*)d_out;
  unsigned short* wbf = (unsigned short*)d_ws;                 // 512 KB
  float* biasws = (float*)((char*)d_ws + 512 * 1024);          // 64 KB

  hipLaunchKernelGGL(prep_kernel, dim3(320), dim3(256), 0, stream,
                     Wch, y, Wy, bch, wbf, biasws);
  hipLaunchKernelGGL(fused_kernel, dim3(2048), dim3(256), 0, stream,
                     x, wbf, biasws, out);
}

// Round 12
// 118.803 us; speedup vs baseline: 1.1650x; 1.0976x over previous
//
#include <hip/hip_runtime.h>

// Problem: BS=64, N=1024, XC=1024, K=256, YS=768
//   y_k[b,k]   = sum_s y[b,s] * W_y[k,s]
//   z[b,n,k]   = tanh( sum_c x[b,n,c]*W_ch[k,c] + b_ch[k] + y_k[b,k] )
//   out[b*n,k] = softmax_k(z)
// bf16 MFMA GEMM (f32 acc) fused with tanh+softmax epilogue.
// R12: R9 base (best, 111.4us) + two serial-chain cuts:
//  (1) staging cvt = biased-round pack (u+0x8000)>>16: VALU halved, same
//      0.5-ulp error as RNE;
//  (2) B staged by global_load_lds DMA (wbf already bf16 frag-ordered:
//      pure linear copy, no VALU, no VGPRs); barrier = lgkm(0)+vmcnt(4)
//      so A(s+3) stays in flight; B read via conflict-free ds_read_b128.

#define XC    1024
#define KOUT  256
#define NT    16        // K-steps: 1024 / 64
#define B_OFF 16384     // byte offset of B double-buffer in LDS
#define LDSZ  81920     // A dbuf 2x8KB + B dbuf 2x32KB

typedef float        f32x4_t  __attribute__((ext_vector_type(4)));
typedef unsigned int u32x4_t  __attribute__((ext_vector_type(4)));
typedef unsigned int u32x2_t  __attribute__((ext_vector_type(2)));
typedef __bf16       bf16x8_t __attribute__((ext_vector_type(8)));

__device__ __forceinline__ unsigned short f2bf(float f) {
  unsigned int u = __float_as_uint(f);
  u += 0x7fffu + ((u >> 16) & 1u);        // RNE (prep kernel only)
  return (unsigned short)(u >> 16);
}

// biased round-half-away pack: 2 floats -> 2 bf16 in one u32. 0.5-ulp max
// error, same as RNE except exact ties (negligible for random data).
__device__ __forceinline__ unsigned int pack2bf(float a, float b) {
  unsigned int ua = __float_as_uint(a) + 0x8000u;
  unsigned int ub = __float_as_uint(b) + 0x8000u;
  return (ua >> 16) | (ub & 0xffff0000u);
}

__device__ __forceinline__ float fast_tanh(float v) {
  float e = __expf(2.0f * v);
  return 1.0f - 2.0f / (e + 1.0f);
}

__device__ __forceinline__ void async_copy16(void* lds, const void* g) {
  // LDS dest: wave-uniform base (+ HW lane*16); global src per-lane.
  __builtin_amdgcn_global_load_lds(
      (const __attribute__((address_space(1))) void*)g,
      (__attribute__((address_space(3))) void*)lds, 16, 0, 0);
}

#define PIPE_WAIT(N) asm volatile("s_waitcnt vmcnt(" #N ")" ::: "memory")

// ---- prep kernel: blocks 0..255 convert W_ch -> fragment-ordered bf16;
//      blocks 256..319 compute bias[b][k] = y[b]·W_y[k] + b_ch[k] (f32).
__global__ void prep_kernel(const float* __restrict__ Wch,
                            const float* __restrict__ y,
                            const float* __restrict__ Wy,
                            const float* __restrict__ bch,
                            unsigned short* __restrict__ wbf,
                            float* __restrict__ biasws) {
  if (blockIdx.x < 256) {
    const int k = blockIdx.x;            // 0..255
    const int u = threadIdx.x;           // 0..255 ; c0 = 4u
    f32x4_t v = ((const f32x4_t*)(Wch + k * XC))[u];
    const int c0   = u << 2;
    const int t    = c0 >> 6;            // K-step tile
    const int ch   = (c0 & 63) >> 3;     // 16B chunk within tile
    const int kk   = ch >> 2;
    const int lg   = ch & 3;
    const int half = (c0 >> 2) & 1;      // which 8B of the 16B chunk
    const int wv   = k >> 6;
    const int ni   = (k >> 4) & 3;
    const int lr   = k & 15;
    const int lane = (lg << 4) | lr;
    unsigned int lo = (unsigned int)f2bf(v.x) | ((unsigned int)f2bf(v.y) << 16);
    unsigned int hi = (unsigned int)f2bf(v.z) | ((unsigned int)f2bf(v.w) << 16);
    char* p = (char*)wbf +
              ((size_t)((((t << 2) + wv) * 2 + kk) * 4 + ni) << 10) +
              (lane << 4) + (half << 3);
    *(u32x2_t*)p = (u32x2_t){lo, hi};
  } else {
    __shared__ __align__(16) float ys[768];
    const int b = blockIdx.x - 256;      // 0..63
    const int k = threadIdx.x;           // 0..255
    for (int i = k; i < 768; i += 256) ys[i] = y[b * 768 + i];
    __syncthreads();
    const f32x4_t* w4 = (const f32x4_t*)(Wy + k * 768);
    const f32x4_t* y4 = (const f32x4_t*)ys;
    float s = 0.f;
#pragma unroll 8
    for (int i = 0; i < 192; ++i) {
      f32x4_t w = w4[i], a = y4[i];
      s = fmaf(w.x, a.x, s); s = fmaf(w.y, a.y, s);
      s = fmaf(w.z, a.z, s); s = fmaf(w.w, a.w, s);
    }
    biasws[b * 256 + k] = s + bch[k];
  }
}

// ---- main fused kernel: 64 rows/block x full 256 cols; BK=64.
// A: reg-staged (3-deep named) biased-round pack, XOR-swizzled ds_write.
// B: global_load_lds DMA of already-bf16 fragment tiles, dbuf LDS.
__global__ __launch_bounds__(256, 2) void fused_kernel(
    const float* __restrict__ x, const unsigned short* __restrict__ wbf,
    const float* __restrict__ bias, float* __restrict__ out) {
  __shared__ __align__(16) unsigned char smem[LDSZ];
  const int tid = threadIdx.x;
  const int l   = tid & 63;
  const int wv  = tid >> 6;            // wave 0..3 -> output cols [64w,64w+64)
  const int lr  = l & 15;
  const int lg  = l >> 4;
  const int m0  = blockIdx.x << 6;     // first of 64 rows
  const int bidx = m0 >> 10;           // batch index
  const int rr  = tid >> 4;            // A-stage: row-within-16-group
  const int c4  = tid & 15;            // A-stage: float4 column chunk
  const int t0  = blockIdx.x & 15;     // per-block K-phase rotation (R9)

  f32x4_t acc[4][4];
#pragma unroll
  for (int i = 0; i < 4; ++i)
#pragma unroll
    for (int j = 0; j < 4; ++j) acc[i][j] = (f32x4_t){0.f, 0.f, 0.f, 0.f};

  const float* xb = x + (size_t)m0 * XC + (size_t)rr * XC + (c4 << 2);
  const char* wsrc = (const char*)wbf;
  f32x4_t av0[4], av1[4], av2[4];      // 3-deep A prefetch, NAMED slots

#define LOADA(dst, tt) do {                                                  \
    _Pragma("unroll")                                                        \
    for (int j = 0; j < 4; ++j)                                              \
      dst[j] = *(const f32x4_t*)(xb + (size_t)(j << 4) * XC + ((tt) << 6));  \
  } while (0)

  // DMA B tile tt (32KB, frag-ordered) into LDS buf: linear copy, 8/wave.
#define DMAB(tt, buf) do {                                                   \
    const char* g = wsrc + (size_t)(tt) * 32768 + (wv << 13) + (l << 4);     \
    unsigned char* d = smem + B_OFF + ((buf) << 15) + (wv << 13);            \
    _Pragma("unroll")                                                        \
    for (int i = 0; i < 8; ++i)                                              \
      async_copy16(d + (i << 10), g + (i << 10));                            \
  } while (0)

#define WRITEA(src, buf) do {                                                \
    _Pragma("unroll")                                                        \
    for (int j = 0; j < 4; ++j) {                                            \
      const int row = (j << 4) + rr;                                         \
      unsigned int lo = pack2bf(src[j].x, src[j].y);                         \
      unsigned int hi = pack2bf(src[j].z, src[j].w);                         \
      char* p = (char*)smem + ((buf) << 13) + row * 128 +                    \
                (((c4 >> 1) ^ (row & 7)) << 4) + ((c4 & 1) << 3);            \
      *(u32x2_t*)p = (u32x2_t){lo, hi};                                      \
    }                                                                        \
  } while (0)

#define COMPUTE(buf) do {                                                    \
    const u32x4_t* aB = (const u32x4_t*)(smem + ((buf) << 13));              \
    const u32x4_t* bB = (const u32x4_t*)(smem + B_OFF + ((buf) << 15));      \
    _Pragma("unroll")                                                        \
    for (int kk = 0; kk < 2; ++kk) {                                         \
      const int cs = ((kk << 2) | lg) ^ (lr & 7);                            \
      bf16x8_t afr[4], bfr[4];                                               \
      _Pragma("unroll")                                                      \
      for (int mi = 0; mi < 4; ++mi)                                         \
        afr[mi] = __builtin_bit_cast(bf16x8_t, aB[(((mi << 4) + lr) << 3) + cs]);\
      _Pragma("unroll")                                                      \
      for (int nj = 0; nj < 4; ++nj)                                         \
        bfr[nj] = __builtin_bit_cast(bf16x8_t,                               \
            bB[((((wv << 3) + (kk << 2) + nj)) << 6) + l]);                  \
      _Pragma("unroll")                                                      \
      for (int mi = 0; mi < 4; ++mi)                                         \
        _Pragma("unroll")                                                    \
        for (int nj = 0; nj < 4; ++nj)                                       \
          acc[mi][nj] = __builtin_amdgcn_mfma_f32_16x16x32_bf16(             \
              afr[mi], bfr[nj], acc[mi][nj], 0, 0, 0);                       \
    }                                                                        \
  } while (0)

  // STEP(s): literal args. aW = av holding A(s+1); aL = slot for A(s+3).
  // Barrier drains lgkm (A ds_writes) + vmcnt to VM: VM=4 leaves A(s+3)
  // in flight while guaranteeing B(s+1) DMA completed (issued this step).
#define STEP(s, aW, aL, VM) do {                                             \
    if ((s) + 1 < NT) DMAB((((s) + 1 + t0) & 15), ((s) + 1) & 1);            \
    if ((s) + 3 < NT) LOADA(aL, (((s) + 3 + t0) & 15));                      \
    COMPUTE((s) & 1);                                                        \
    if ((s) + 1 < NT) {                                                      \
      WRITEA(aW, ((s) + 1) & 1);                                             \
      asm volatile("s_waitcnt lgkmcnt(0)" ::: "memory");                     \
      PIPE_WAIT(VM);                                                         \
      __builtin_amdgcn_s_barrier();                                          \
      __builtin_amdgcn_sched_barrier(0);                                     \
    }                                                                        \
  } while (0)

  // prologue: B(t0) DMA first (oldest), then A(t0..t0+2); staging A(t0)
  // auto-drains av0 AND the older B-DMA; then publish via barrier.
  DMAB(t0, 0);
  LOADA(av0, t0);
  LOADA(av1, (t0 + 1) & 15);
  LOADA(av2, (t0 + 2) & 15);
  WRITEA(av0, 0);          // waits av0 (drains B(t0) too); av1,av2 in flight
  asm volatile("s_waitcnt lgkmcnt(0)" ::: "memory");
  __builtin_amdgcn_s_barrier();
  __builtin_amdgcn_sched_barrier(0);

  STEP( 0, av1, av0, 4);
  STEP( 1, av2, av1, 4);
  STEP( 2, av0, av2, 4);
  STEP( 3, av1, av0, 4);
  STEP( 4, av2, av1, 4);
  STEP( 5, av0, av2, 4);
  STEP( 6, av1, av0, 4);
  STEP( 7, av2, av1, 4);
  STEP( 8, av0, av2, 4);
  STEP( 9, av1, av0, 4);
  STEP(10, av2, av1, 4);
  STEP(11, av0, av2, 4);
  STEP(12, av1, av0, 4);
  STEP(13, av2, av1, 0);   // no LOADA (s+3=16): drain to 0 (only B left)
  STEP(14, av0, av0, 0);   // last staged tile; drain B(15)
  STEP(15, av0, av0, 0);   // compute only

  __syncthreads();             // full drain before scratch aliases A buffer

#undef LOADA
#undef DMAB
#undef WRITEA
#undef COMPUTE
#undef STEP

  // ---- epilogue: tanh, row-softmax over 256 cols, store
  float* wred    = (float*)smem;           // [4 waves][64 rows]
  float* rowstat = (float*)(smem + 1024);  // [64 rows]

  float brow[4];
#pragma unroll
  for (int ni = 0; ni < 4; ++ni)
    brow[ni] = bias[(bidx << 8) + (wv << 6) + (ni << 4) + lr];

#pragma unroll
  for (int mi = 0; mi < 4; ++mi)
#pragma unroll
    for (int ni = 0; ni < 4; ++ni)
#pragma unroll
      for (int r = 0; r < 4; ++r)
        acc[mi][ni][r] = fast_tanh(acc[mi][ni][r] + brow[ni]);

  // per-row max: 4 local cols, then butterfly over the 16-lane col group
#pragma unroll
  for (int mi = 0; mi < 4; ++mi)
#pragma unroll
    for (int r = 0; r < 4; ++r) {
      float m = fmaxf(fmaxf(acc[mi][0][r], acc[mi][1][r]),
                      fmaxf(acc[mi][2][r], acc[mi][3][r]));
      m = fmaxf(m, __shfl_xor(m, 1));
      m = fmaxf(m, __shfl_xor(m, 2));
      m = fmaxf(m, __shfl_xor(m, 4));
      m = fmaxf(m, __shfl_xor(m, 8));
      if (lr == 0) wred[(wv << 6) + (mi << 4) + (lg << 2) + r] = m;
    }
  __syncthreads();
  if (tid < 64)
    rowstat[tid] = fmaxf(fmaxf(wred[tid], wred[64 + tid]),
                         fmaxf(wred[128 + tid], wred[192 + tid]));
  __syncthreads();

  // exp + per-row sum
#pragma unroll
  for (int mi = 0; mi < 4; ++mi)
#pragma unroll
    for (int r = 0; r < 4; ++r) {
      const int row = (mi << 4) + (lg << 2) + r;
      const float m = rowstat[row];
      float s = 0.f;
#pragma unroll
      for (int ni = 0; ni < 4; ++ni) {
        float e = __expf(acc[mi][ni][r] - m);
        acc[mi][ni][r] = e;
        s += e;
      }
      s += __shfl_xor(s, 1);
      s += __shfl_xor(s, 2);
      s += __shfl_xor(s, 4);
      s += __shfl_xor(s, 8);
      if (lr == 0) wred[(wv << 6) + row] = s;
    }
  __syncthreads();
  if (tid < 64)
    rowstat[tid] = 1.0f / (wred[tid] + wred[64 + tid] +
                           wred[128 + tid] + wred[192 + tid]);
  __syncthreads();

  // normalize + store (16 lanes = 64B dense segments)
#pragma unroll
  for (int mi = 0; mi < 4; ++mi)
#pragma unroll
    for (int r = 0; r < 4; ++r) {
      const int row = (mi << 4) + (lg << 2) + r;
      const float rinv = rowstat[row];
      float* orow = out + (size_t)(m0 + row) * KOUT + (wv << 6) + lr;
#pragma unroll
      for (int ni = 0; ni < 4; ++ni)
        orow[ni << 4] = acc[mi][ni][r] * rinv;
    }
}

extern "C" void kernel_launch(void* const* d_in, const int* in_sizes, int n_in,
                              void* d_out, int out_size, void* d_ws, size_t ws_size,
                              hipStream_t stream) {
  (void)in_sizes; (void)n_in; (void)out_size; (void)ws_size;
  const float* x   = (const float*)d_in[0];
  const float* y   = (const float*)d_in[1];
  const float* Wch = (const float*)d_in[2];
  const float* bch = (const float*)d_in[3];
  const float* Wy  = (const float*)d_in[4];
  float* out = (float*)d_out;
  unsigned short* wbf = (unsigned short*)d_ws;                 // 512 KB
  float* biasws = (float*)((char*)d_ws + 512 * 1024);          // 64 KB

  hipLaunchKernelGGL(prep_kernel, dim3(320), dim3(256), 0, stream,
                     Wch, y, Wy, bch, wbf, biasws);
  hipLaunchKernelGGL(fused_kernel, dim3(1024), dim3(256), 0, stream,
                     x, wbf, biasws, out);
}